// Round 1
// baseline (213.347 us; speedup 1.0000x reference)
//
#include <hip/hip_runtime.h>

// GCN on 100K nodes / 1.6M edges, but output depends only on node_index's
// 3-hop in-neighborhood. Strategy: frontier-restricted computation.
//   F1 = in(n0) u {n0}            (~17 nodes)  -> need h2 here
//   F2 = in(F1) u F1              (~290 nodes) -> need h1 here
//   layer-1 agg only for edges with dst in F2  (~4.7K of 1.6M edges)
// deg[] (in-degree+1) still needs a full edge scan (normalization uses the
// true degree of every endpoint).
//
// Compact storage: slot1[node] -> row in h1c (cap 8192), slot2 -> h2c (2048).
// Edge dtype (int64 per reference, int32 if harness downcasts) detected on
// device by probing high words of the first 64 entries.

#define HID  64
#define CAP1 8192
#define CAP2 2048

__device__ __forceinline__ int ld_idx(const void* p, int is64, long long i) {
  return is64 ? (int)((const long long*)p)[i] : ((const int*)p)[i];
}

__global__ void k_detect(const unsigned int* e32, int* flag) {
  if (blockIdx.x == 0 && threadIdx.x == 0) {
    int is64 = 1;
    for (int i = 0; i < 64; ++i)
      if (e32[2 * i + 1] != 0u) { is64 = 0; break; }
    *flag = is64;
  }
}

__global__ void k_init(int N, int* deg, int* slot1, int* slot2,
                       float* h1c, float* h2c, float* h3acc,
                       int* cnt1, int* cnt2) {
  int i = blockIdx.x * blockDim.x + threadIdx.x;
  if (i < N) { deg[i] = 0; slot1[i] = -1; slot2[i] = -1; }
  if (i < CAP1 * HID) h1c[i] = 0.f;
  if (i < CAP2 * HID) h2c[i] = 0.f;
  if (i < HID) h3acc[i] = 0.f;
  if (i == 0) { *cnt1 = 0; *cnt2 = 0; }
}

// deg histogram + F1 discovery (src of edges whose dst == node_index)
__global__ void k_scan1(const void* ei, int E, const int* flag, const int* nidx_p,
                        int* deg, int* slot2, int* cnt2) {
  int e = blockIdx.x * blockDim.x + threadIdx.x;
  if (e >= E) return;
  int is64 = *flag;
  int d = ld_idx(ei, is64, (long long)E + e);
  atomicAdd(&deg[d], 1);
  if (d == *nidx_p) {
    int s = ld_idx(ei, is64, e);
    if (atomicCAS(&slot2[s], -1, -2) == -1)
      slot2[s] = atomicAdd(cnt2, 1) & (CAP2 - 1);
  }
}

// dinv; seed node_index into F1; copy F1 into F2
__global__ void k_node2(int N, const int* nidx_p, const int* deg, float* dinv,
                        int* slot1, int* slot2, int* cnt1, int* cnt2) {
  int i = blockIdx.x * blockDim.x + threadIdx.x;
  if (i >= N) return;
  dinv[i] = 1.0f / sqrtf((float)(deg[i] + 1));
  if (i == *nidx_p) {
    if (atomicCAS(&slot2[i], -1, -2) == -1)
      slot2[i] = atomicAdd(cnt2, 1) & (CAP2 - 1);
  }
  if (slot2[i] >= 0) {  // F1 subset of F2 (self-loop at layer 2 needs h1)
    if (atomicCAS(&slot1[i], -1, -2) == -1)
      slot1[i] = atomicAdd(cnt1, 1) & (CAP1 - 1);
  }
}

// F2 discovery: src of edges whose dst is in F1
__global__ void k_scan3(const void* ei, int E, const int* flag,
                        const int* slot2, int* slot1, int* cnt1) {
  int e = blockIdx.x * blockDim.x + threadIdx.x;
  if (e >= E) return;
  int is64 = *flag;
  int d = ld_idx(ei, is64, (long long)E + e);
  if (slot2[d] >= 0) {
    int s = ld_idx(ei, is64, e);
    if (atomicCAS(&slot1[s], -1, -2) == -1)
      slot1[s] = atomicAdd(cnt1, 1) & (CAP1 - 1);
  }
}

// layer-1 aggregation: edges with dst in F2. Wave-cooperative: lanes ballot
// active edges, then all 64 lanes compute the 64-wide message together.
__global__ void k_agg1(const void* ei, int E, const int* flag, const float* x,
                       const float* W1, const float* dinv, const int* slot1,
                       float* h1c) {
  int e = blockIdx.x * blockDim.x + threadIdx.x;
  int lane = threadIdx.x & 63;
  int is64 = *flag;
  bool act = false;
  int sd = -1, s_l = 0; float c_l = 0.f;
  if (e < E) {
    int d = ld_idx(ei, is64, (long long)E + e);
    sd = slot1[d];
    if (sd >= 0) {
      act = true;
      int s = ld_idx(ei, is64, e);
      s_l = s;
      c_l = dinv[s] * dinv[d];
    }
  }
  unsigned long long mask = __ballot(act);
  while (mask) {
    int l = __ffsll(mask) - 1; mask &= mask - 1;
    int ss = __shfl(s_l, l);
    int dd = __shfl(sd, l);
    float c = __shfl(c_l, l);
    float m = 0.f;
#pragma unroll
    for (int k = 0; k < 4; ++k) m += x[ss * 4 + k] * W1[k * HID + lane];
    atomicAdd(&h1c[dd * HID + lane], c * m);
  }
}

// finalize h1 for F2 nodes: add self-loop term + bias, relu (in place)
__global__ void k_fin1(int N, const float* x, const float* W1, const float* b1,
                       const float* dinv, const int* slot1, float* h1c) {
  int i = blockIdx.x * blockDim.x + threadIdx.x;
  int lane = threadIdx.x & 63;
  bool act = false; int s1 = -1, ii = 0; float c = 0.f;
  if (i < N) {
    s1 = slot1[i];
    if (s1 >= 0) { act = true; float di = dinv[i]; c = di * di; ii = i; }
  }
  unsigned long long mask = __ballot(act);
  while (mask) {
    int l = __ffsll(mask) - 1; mask &= mask - 1;
    int node = __shfl(ii, l);
    int slot = __shfl(s1, l);
    float cc = __shfl(c, l);
    float m = 0.f;
#pragma unroll
    for (int k = 0; k < 4; ++k) m += x[node * 4 + k] * W1[k * HID + lane];
    float v = h1c[slot * HID + lane] + cc * m + b1[lane];
    h1c[slot * HID + lane] = v > 0.f ? v : 0.f;
  }
}

// layer-2 aggregation: edges with dst in F1 (src guaranteed in F2)
__global__ void k_agg2(const void* ei, int E, const int* flag, const float* W2,
                       const float* dinv, const int* slot1, const int* slot2,
                       const float* h1c, float* h2c) {
  int e = blockIdx.x * blockDim.x + threadIdx.x;
  int lane = threadIdx.x & 63;
  int is64 = *flag;
  bool act = false;
  int sd2 = -1, ss1 = 0; float c_l = 0.f;
  if (e < E) {
    int d = ld_idx(ei, is64, (long long)E + e);
    sd2 = slot2[d];
    if (sd2 >= 0) {
      act = true;
      int s = ld_idx(ei, is64, e);
      ss1 = slot1[s];
      c_l = dinv[s] * dinv[d];
    }
  }
  unsigned long long mask = __ballot(act);
  while (mask) {
    int l = __ffsll(mask) - 1; mask &= mask - 1;
    int as1 = __shfl(ss1, l);
    int ad2 = __shfl(sd2, l);
    float c = __shfl(c_l, l);
    float m = 0.f;
#pragma unroll 16
    for (int k = 0; k < HID; ++k) m += h1c[as1 * HID + k] * W2[k * HID + lane];
    atomicAdd(&h2c[ad2 * HID + lane], c * m);
  }
}

// finalize h2 for F1 nodes
__global__ void k_fin2(int N, const float* W2, const float* b2,
                       const float* dinv, const int* slot1, const int* slot2,
                       const float* h1c, float* h2c) {
  int i = blockIdx.x * blockDim.x + threadIdx.x;
  int lane = threadIdx.x & 63;
  bool act = false; int s1 = 0, s2 = -1; float c = 0.f;
  if (i < N) {
    s2 = slot2[i];
    if (s2 >= 0) { act = true; s1 = slot1[i]; float di = dinv[i]; c = di * di; }
  }
  unsigned long long mask = __ballot(act);
  while (mask) {
    int l = __ffsll(mask) - 1; mask &= mask - 1;
    int as1 = __shfl(s1, l);
    int as2 = __shfl(s2, l);
    float cc = __shfl(c, l);
    float m = 0.f;
#pragma unroll 16
    for (int k = 0; k < HID; ++k) m += h1c[as1 * HID + k] * W2[k * HID + lane];
    float v = h2c[as2 * HID + lane] + cc * m + b2[lane];
    h2c[as2 * HID + lane] = v > 0.f ? v : 0.f;
  }
}

// layer-3 aggregation: edges with dst == node_index (src guaranteed in F1)
__global__ void k_agg3(const void* ei, int E, const int* flag, const int* nidx_p,
                       const float* W3, const float* dinv, const int* slot2,
                       const float* h2c, float* h3acc) {
  int e = blockIdx.x * blockDim.x + threadIdx.x;
  int lane = threadIdx.x & 63;
  int is64 = *flag;
  int nidx = *nidx_p;
  bool act = false;
  int ss2 = 0; float c_l = 0.f;
  if (e < E) {
    int d = ld_idx(ei, is64, (long long)E + e);
    if (d == nidx) {
      act = true;
      int s = ld_idx(ei, is64, e);
      ss2 = slot2[s];
      c_l = dinv[s] * dinv[d];
    }
  }
  unsigned long long mask = __ballot(act);
  while (mask) {
    int l = __ffsll(mask) - 1; mask &= mask - 1;
    int as2 = __shfl(ss2, l);
    float c = __shfl(c_l, l);
    float m = 0.f;
#pragma unroll 16
    for (int k = 0; k < HID; ++k) m += h2c[as2 * HID + k] * W3[k * HID + lane];
    atomicAdd(&h3acc[lane], c * m);
  }
}

// head: finalize h3[n0], MLP, 4 output projections -> 19 floats
__global__ void k_head(const int* nidx_p, const int* slot2, const float* dinv,
                       const float* h2c, const float* h3acc,
                       const float* W3, const float* b3,
                       const float* Wp, const float* bp,
                       const float* Wa, const float* ba,
                       const float* Wm, const float* bm,
                       const float* Wg, const float* bg,
                       const float* Wt, const float* bt, float* out) {
  __shared__ float h3[HID];
  __shared__ float p[HID];
  int j = threadIdx.x;
  int nidx = *nidx_p;
  int s2 = slot2[nidx];
  float di = dinv[nidx];
  float m = 0.f;
#pragma unroll 16
  for (int k = 0; k < HID; ++k) m += h2c[s2 * HID + k] * W3[k * HID + j];
  float v = h3acc[j] + di * di * m + b3[j];
  h3[j] = v > 0.f ? v : 0.f;
  __syncthreads();
  float pv = bp[j];
#pragma unroll 16
  for (int k = 0; k < HID; ++k) pv += h3[k] * Wp[k * HID + j];
  p[j] = pv > 0.f ? pv : 0.f;
  __syncthreads();
  if (j < 4) {
    float o = ba[j];
    for (int k = 0; k < HID; ++k) o += p[k] * Wa[k * 4 + j];
    out[j] = o;
  } else if (j < 6) {
    int c = j - 4; float o = bm[c];
    for (int k = 0; k < HID; ++k) o += p[k] * Wm[k * 2 + c];
    out[j] = o;
  } else if (j < 9) {
    int c = j - 6; float o = bg[c];
    for (int k = 0; k < HID; ++k) o += p[k] * Wg[k * 3 + c];
    out[j] = o;
  } else if (j < 19) {
    int c = j - 9; float o = bt[c];
    for (int k = 0; k < HID; ++k) o += p[k] * Wt[k * 10 + c];
    out[j] = o;
  }
}

extern "C" void kernel_launch(void* const* d_in, const int* in_sizes, int n_in,
                              void* d_out, int out_size, void* d_ws, size_t ws_size,
                              hipStream_t stream) {
  const float* x  = (const float*)d_in[0];
  const void*  ei = d_in[1];
  const int* nidx = (const int*)d_in[2];
  const float* W1 = (const float*)d_in[3];
  const float* b1 = (const float*)d_in[4];
  const float* W2 = (const float*)d_in[5];
  const float* b2 = (const float*)d_in[6];
  const float* W3 = (const float*)d_in[7];
  const float* b3 = (const float*)d_in[8];
  const float* Wp = (const float*)d_in[9];
  const float* bp = (const float*)d_in[10];
  const float* Wa = (const float*)d_in[11];
  const float* ba = (const float*)d_in[12];
  const float* Wm = (const float*)d_in[13];
  const float* bm = (const float*)d_in[14];
  const float* Wg = (const float*)d_in[15];
  const float* bg = (const float*)d_in[16];
  const float* Wt = (const float*)d_in[17];
  const float* bt = (const float*)d_in[18];
  float* out = (float*)d_out;

  int N = in_sizes[0] / 4;   // 100000
  int E = in_sizes[1] / 2;   // 1600000

  char* w = (char*)d_ws;
  size_t o = 0;
  auto take = [&](size_t bytes) -> void* {
    void* p = w + o;
    o += (bytes + 255) & ~(size_t)255;
    return p;
  };
  int*   flag  = (int*)take(4);
  int*   cnt1  = (int*)take(4);
  int*   cnt2  = (int*)take(4);
  int*   deg   = (int*)take((size_t)N * 4);
  float* dinv  = (float*)take((size_t)N * 4);
  int*   slot1 = (int*)take((size_t)N * 4);
  int*   slot2 = (int*)take((size_t)N * 4);
  float* h1c   = (float*)take((size_t)CAP1 * HID * 4);
  float* h2c   = (float*)take((size_t)CAP2 * HID * 4);
  float* h3acc = (float*)take(HID * 4);

  int gE = (E + 255) / 256;
  int gN = (N + 255) / 256;
  int initN = CAP1 * HID > N ? CAP1 * HID : N;
  int gI = (initN + 255) / 256;

  k_detect<<<1, 64, 0, stream>>>((const unsigned int*)ei, flag);
  k_init  <<<gI, 256, 0, stream>>>(N, deg, slot1, slot2, h1c, h2c, h3acc, cnt1, cnt2);
  k_scan1 <<<gE, 256, 0, stream>>>(ei, E, flag, nidx, deg, slot2, cnt2);
  k_node2 <<<gN, 256, 0, stream>>>(N, nidx, deg, dinv, slot1, slot2, cnt1, cnt2);
  k_scan3 <<<gE, 256, 0, stream>>>(ei, E, flag, slot2, slot1, cnt1);
  k_agg1  <<<gE, 256, 0, stream>>>(ei, E, flag, x, W1, dinv, slot1, h1c);
  k_fin1  <<<gN, 256, 0, stream>>>(N, x, W1, b1, dinv, slot1, h1c);
  k_agg2  <<<gE, 256, 0, stream>>>(ei, E, flag, W2, dinv, slot1, slot2, h1c, h2c);
  k_fin2  <<<gN, 256, 0, stream>>>(N, W2, b2, dinv, slot1, slot2, h1c, h2c);
  k_agg3  <<<gE, 256, 0, stream>>>(ei, E, flag, nidx, W3, dinv, slot2, h2c, h3acc);
  k_head  <<<1, HID, 0, stream>>>(nidx, slot2, dinv, h2c, h3acc, W3, b3, Wp, bp,
                                  Wa, ba, Wm, bm, Wg, bg, Wt, bt, out);
}